// Round 1
// baseline (129.288 us; speedup 1.0000x reference)
//
#include <hip/hip_runtime.h>

// Problem constants (from setup_inputs): B=64, C=4, H=W=256, N=128
constexpr int Bimg = 64;
constexpr int C    = 4;
constexpr int Hh   = 256;
constexpr int Ww   = 256;
constexpr int Np   = 128;
constexpr int HW   = Hh * Ww;

constexpr float PULL_W = 0.25f;
constexpr float PUSH_W = 0.25f;

__global__ void ae_init_out(float* out) {
    out[0] = 0.0f;
    out[1] = 0.0f;
}

// One block per image, one thread per match point.
__global__ __launch_bounds__(Np) void ae_loss_kernel(
        const float* __restrict__ pred,     // (B,C,H,W)
        const float* __restrict__ target,   // (B,C,H,W)
        const int*   __restrict__ match,    // (B,N,2,2)
        float* __restrict__ out)            // [pull_all, push_all]
{
    const int b = blockIdx.x;
    const int n = threadIdx.x;

    __shared__ float s_sh[Np];
    __shared__ float red_pull[2];
    __shared__ float red_push[2];

    // match[b][n][p][q]: 4 consecutive ints, 16B aligned
    const int4 m = *reinterpret_cast<const int4*>(match + ((size_t)(b * Np + n)) * 4);
    const int tl_off = m.x * Ww + m.y;   // tl_y*W + tl_x
    const int br_off = m.z * Ww + m.w;   // br_y*W + br_x

    const float* pb = pred   + (size_t)b * C * HW;
    const float* tb = target + (size_t)b * C * HW;

    float pull = 0.0f;
    float s    = 0.0f;
#pragma unroll
    for (int c = 0; c < C; ++c) {
        const float tl = pb[c * HW + tl_off];
        const float br = tb[c * HW + br_off];
        const float d  = tl - br;
        pull += d * d;          // (tl-me)^2 + (br-me)^2 = d^2/2, fold /2 below
        s    += tl + br;        // me-sum * 2, fold *0.5 below
    }
    pull *= 0.5f;
    s    *= 0.5f;

    s_sh[n] = s;
    __syncthreads();

    // push: sum_{j != n} relu(1 - |s_n - s_j|)
    float push = 0.0f;
#pragma unroll 8
    for (int j = 0; j < Np; ++j) {
        const float v = 1.0f - fabsf(s - s_sh[j]);
        if (j != n && v > 0.0f) push += v;
    }

    // wave (64-lane) reduction
#pragma unroll
    for (int off = 32; off > 0; off >>= 1) {
        pull += __shfl_down(pull, off, 64);
        push += __shfl_down(push, off, 64);
    }
    const int lane = n & 63;
    const int wv   = n >> 6;          // 2 waves per block
    if (lane == 0) {
        red_pull[wv] = pull;
        red_push[wv] = push;
    }
    __syncthreads();

    if (n == 0) {
        const float pull_b = red_pull[0] + red_pull[1];
        const float push_b = red_push[0] + red_push[1];
        atomicAdd(out + 0, pull_b * (PULL_W / (float)Np));
        atomicAdd(out + 1, push_b * (PUSH_W / ((float)Np * (float)(Np - 1))));
    }
}

extern "C" void kernel_launch(void* const* d_in, const int* in_sizes, int n_in,
                              void* d_out, int out_size, void* d_ws, size_t ws_size,
                              hipStream_t stream) {
    const float* pred   = (const float*)d_in[0];
    const float* target = (const float*)d_in[1];
    const int*   match  = (const int*)d_in[2];
    float* out = (float*)d_out;

    ae_init_out<<<1, 1, 0, stream>>>(out);
    ae_loss_kernel<<<Bimg, Np, 0, stream>>>(pred, target, match, out);
}